// Round 12
// baseline (3247.480 us; speedup 1.0000x reference)
//
#include <hip/hip_runtime.h>

#define PAD_IDX 0

typedef __attribute__((ext_vector_type(8))) short short8;
typedef __attribute__((ext_vector_type(4))) float f32x4;

// ---------- helpers ----------
__device__ __forceinline__ unsigned short f32_to_bf16_rne(float f) {
  unsigned int u = __builtin_bit_cast(unsigned int, f);
  u += 0x7FFFu + ((u >> 16) & 1u);
  return (unsigned short)(u >> 16);
}

__device__ __forceinline__ void load16_to_lds(const void* g, void* lds) {
  __builtin_amdgcn_global_load_lds(
      (const __attribute__((address_space(1))) unsigned int*)g,
      (__attribute__((address_space(3))) unsigned int*)lds,
      16, 0, 0);
}

// ---------- kernel 0: sentinel (only if ws too small) ----------
__global__ void sentinel_kernel(float* out) { out[0] = 1.0e6f; }

// ---------- kernel 1: merged xw + cvt (R10-proven) ----------
__global__ __launch_bounds__(256) void xwcvt_kernel(const int* __restrict__ tok,
                                                    const float* __restrict__ emb,
                                                    const float* __restrict__ Wx,
                                                    const float* __restrict__ bias,
                                                    float* __restrict__ xw,
                                                    const float* __restrict__ lmW,
                                                    unsigned short* __restrict__ lmW_bf) {
  int tid = threadIdx.x;
  if (blockIdx.x >= 1024) {
    const int n8 = 32000 * 1024 / 8;
    int stride = 512 * 256;
    for (int i = (blockIdx.x - 1024) * 256 + tid; i < n8; i += stride) {
      float4 a = ((const float4*)lmW)[2 * i];
      float4 b = ((const float4*)lmW)[2 * i + 1];
      ushort4 lo, hi;
      lo.x = f32_to_bf16_rne(a.x); lo.y = f32_to_bf16_rne(a.y);
      lo.z = f32_to_bf16_rne(a.z); lo.w = f32_to_bf16_rne(a.w);
      hi.x = f32_to_bf16_rne(b.x); hi.y = f32_to_bf16_rne(b.y);
      hi.z = f32_to_bf16_rne(b.z); hi.w = f32_to_bf16_rne(b.w);
      ((ushort4*)lmW_bf)[2 * i] = lo;
      ((ushort4*)lmW_bf)[2 * i + 1] = hi;
    }
    return;
  }
  __shared__ float At[32][68];
  __shared__ float Bt[32][68];
  __shared__ int stok[64];
  int tm = blockIdx.x & 63;
  int tn = blockIdx.x >> 6;
  int r0 = tm * 64, j0 = tn * 64;
  if (tid < 64) stok[tid] = tok[r0 + tid];
  int tx = tid & 15, ty = tid >> 4;
  float acc[4][4] = {};
  for (int kt = 0; kt < 512; kt += 32) {
    __syncthreads();
    #pragma unroll
    for (int ii = 0; ii < 2; ++ii) {
      int idx = tid * 2 + ii;
      int m = idx >> 3, fv = idx & 7;
      float4 va = *(const float4*)&emb[(size_t)stok[m] * 512 + kt + fv * 4];
      float4 vb = *(const float4*)&Wx[(size_t)(j0 + m) * 512 + kt + fv * 4];
      At[fv * 4 + 0][m] = va.x; At[fv * 4 + 1][m] = va.y;
      At[fv * 4 + 2][m] = va.z; At[fv * 4 + 3][m] = va.w;
      Bt[fv * 4 + 0][m] = vb.x; Bt[fv * 4 + 1][m] = vb.y;
      Bt[fv * 4 + 2][m] = vb.z; Bt[fv * 4 + 3][m] = vb.w;
    }
    __syncthreads();
    #pragma unroll
    for (int k = 0; k < 32; ++k) {
      float4 a4 = *(const float4*)&At[k][ty * 4];
      float4 b4 = *(const float4*)&Bt[k][tx * 4];
      float av[4] = {a4.x, a4.y, a4.z, a4.w};
      float bv[4] = {b4.x, b4.y, b4.z, b4.w};
      #pragma unroll
      for (int i = 0; i < 4; ++i)
        #pragma unroll
        for (int jj = 0; jj < 4; ++jj) acc[i][jj] = fmaf(av[i], bv[jj], acc[i][jj]);
    }
  }
  #pragma unroll
  for (int i = 0; i < 4; ++i) {
    size_t row = (size_t)(r0 + ty * 4 + i) * 1024 + j0 + tx * 4;
    #pragma unroll
    for (int jj = 0; jj < 4; ++jj)
      xw[row + jj] = acc[i][jj] + bias[j0 + tx * 4 + jj];
  }
}

// ---------- kernel 2: merged recurrence + overlapped GEMM ----------
// Blocks 0..255: REC role (R10-proven inner loop). h_all layout CHANGED to row
// R = t*16+c so M-tiles become progressively ready. Every 8 steps the writer
// wave fences (threadfence: wb for cross-XCD) and tid0 releases prog[t>>3].
// Blocks 256..8255: GEMM role, 128x128xBK64 tile, mtile-major (gb/250), polls
// prog[mtile]==256 -> threadfence (inv stale L2) -> proven counted-vmcnt
// pipeline. C rows remapped: R=t*16+c -> Crow=(R&15)*256+(R>>4).
// Co-residency: uniform 64KB LDS -> CU = 1 rec + 1 gemm (3 blocks impossible);
// tid>=512 of gemm blocks exit before any barrier. Guards fail loud, not hung.
__global__ __launch_bounds__(1024) void recgemm_kernel(const float* __restrict__ Wh,
                                                       const float* __restrict__ xw,
                                                       const int* __restrict__ tok,
                                                       unsigned long long* hcomb,  // [2][16][1024]
                                                       unsigned short* h_all,      // [256*16][1024] R=t*16+c
                                                       const unsigned short* __restrict__ Bm,  // lmW_bf
                                                       float* __restrict__ C,
                                                       unsigned int* prog) {       // [32]
  __shared__ __align__(16) char smem[65536];
  int bid = blockIdx.x;
  int tid = threadIdx.x;

  if (bid < 256) {
    // ================= REC role =================
    int c = bid & 15;
    int g = bid >> 4;
    int w = tid >> 6;
    int l = tid & 63;
    int j = g * 64 + l;

    const float* wb = Wh + (size_t)j * 1024 + w * 64;
#define LDW(i) f32x4 w##i = *(const f32x4*)(wb + i * 4);
    LDW(0) LDW(1) LDW(2) LDW(3) LDW(4) LDW(5) LDW(6) LDW(7)
    LDW(8) LDW(9) LDW(10) LDW(11) LDW(12) LDW(13) LDW(14) LDW(15)
#undef LDW

    float* hs = (float*)smem;            // [16][64]
    float* pbuf = hs + 16 * 64;          // [16][64]
    unsigned long long* hc0 = hcomb + (size_t)c * 1024;
    unsigned long long* hc1 = hcomb + 16 * 1024 + (size_t)c * 1024;
    bool writer = (w == 0);
    float prevh = 0.f;

    for (int t = 0; t < 256; ++t) {
      float xv = 0.f;
      int tkn = 1;
      if (writer) {
        xv = xw[((size_t)c * 256 + t) * 1024 + j];
        tkn = tok[c * 256 + t];
      }
      unsigned long long* src = ((t & 1) ? hc1 : hc0) + tid;
      unsigned long long v;
      int guard = 0;
      do {
        v = __hip_atomic_load(src, __ATOMIC_RELAXED, __HIP_MEMORY_SCOPE_AGENT);
        if ((unsigned int)(v >> 32) == (unsigned int)t) break;
        __builtin_amdgcn_s_sleep(1);
      } while (++guard < (1 << 20));  // fail loud, not hung
      hs[w * 64 + l] = __builtin_bit_cast(float, (unsigned int)v);
      __asm__ volatile("s_waitcnt lgkmcnt(0)" ::: "memory");  // wave-local share

      const float* hp = hs + w * 64;
      f32x4 a0 = {0.f, 0.f, 0.f, 0.f}, a1 = a0, a2 = a0, a3 = a0;
#define FMAI(i, acc) { f32x4 h4 = *(const f32x4*)(hp + i * 4); acc += w##i * h4; }
      FMAI(0, a0) FMAI(1, a1) FMAI(2, a2) FMAI(3, a3)
      FMAI(4, a0) FMAI(5, a1) FMAI(6, a2) FMAI(7, a3)
      FMAI(8, a0) FMAI(9, a1) FMAI(10, a2) FMAI(11, a3)
      FMAI(12, a0) FMAI(13, a1) FMAI(14, a2) FMAI(15, a3)
#undef FMAI
      f32x4 aa = (a0 + a1) + (a2 + a3);
      pbuf[w * 64 + l] = (aa[0] + aa[1]) + (aa[2] + aa[3]);
      __asm__ volatile("s_waitcnt lgkmcnt(0)\n\ts_barrier" ::: "memory");

      if (writer) {
        float s = 0.f;
        #pragma unroll
        for (int q = 0; q < 16; ++q) s += pbuf[q * 64 + l];
        float hnew;
        if (tkn != PAD_IDX) {
          float pre = xv + s;
          float e = __builtin_amdgcn_exp2f(pre * 2.8853900817779268f);  // exp(2x)
          hnew = 1.0f - 2.0f / (e + 1.0f);                              // tanh(x)
        } else {
          hnew = prevh;
        }
        prevh = hnew;
        unsigned long long pv =
            ((unsigned long long)(unsigned int)(t + 1) << 32) |
            (unsigned long long)__builtin_bit_cast(unsigned int, hnew);
        __hip_atomic_store((((t + 1) & 1) ? hc1 : hc0) + j, pv,
                           __ATOMIC_RELAXED, __HIP_MEMORY_SCOPE_AGENT);
        h_all[((size_t)t * 16 + c) * 1024 + j] = f32_to_bf16_rne(hnew);
        if ((t & 7) == 7) {
          __threadfence();  // writer wave: h_all stores visible agent-wide
          if (tid == 0)
            __hip_atomic_fetch_add(prog + (t >> 3), 1u,
                                   __ATOMIC_RELAXED, __HIP_MEMORY_SCOPE_AGENT);
        }
      }
    }
    return;
  }

  // ================= GEMM role =================
  if (tid >= 512) return;  // exits before any barrier; 8 live waves remain
  int gb = bid - 256;
  int mtile = gb / 250, ntile = gb - mtile * 250;
  int r0 = mtile * 128, c0 = ntile * 128;
  int lane = tid & 63, wave = tid >> 6;
  int wm = wave >> 2, wn = wave & 3;  // 2M x 4N; per-wave 64x32

  {
    long guard = 0;
    while (__hip_atomic_load(prog + mtile, __ATOMIC_RELAXED, __HIP_MEMORY_SCOPE_AGENT) < 256u) {
      __builtin_amdgcn_s_sleep(1);
      if (++guard > (1L << 24)) break;  // fail loud, not hung
    }
  }
  __threadfence();  // invalidate stale h_all lines in this XCD's caches

  unsigned short* ldsb = (unsigned short*)smem;
  const unsigned short* A = h_all;

  auto STAGE = [&](int kt, int st) {
    unsigned short* bufA = ldsb + st * 16384;
    unsigned short* bufB = bufA + 8192;
    #pragma unroll
    for (int i = 0; i < 2; ++i) {
      int slot = i * 512 + tid;        // 0..1023 = 128 rows x 8 granules
      int row = slot >> 3, sg = slot & 7;
      int kg = sg ^ (row & 7);
      const unsigned short* ga = A + (size_t)(r0 + row) * 1024 + kt * 64 + kg * 8;
      load16_to_lds(ga, &bufA[(i * 512 + wave * 64) * 8]);
    }
    #pragma unroll
    for (int i = 0; i < 2; ++i) {
      int slot = i * 512 + tid;
      int row = slot >> 3, sg = slot & 7;
      int kg = sg ^ (row & 7);
      const unsigned short* gb2 = Bm + (size_t)(c0 + row) * 1024 + kt * 64 + kg * 8;
      load16_to_lds(gb2, &bufB[(i * 512 + wave * 64) * 8]);
    }
  };

  f32x4 zero = {0.f, 0.f, 0.f, 0.f};
  f32x4 acc[4][2];
  #pragma unroll
  for (int i = 0; i < 4; ++i)
    #pragma unroll
    for (int jx = 0; jx < 2; ++jx) acc[i][jx] = zero;

  STAGE(0, 0);
  STAGE(1, 1);
  __asm__ volatile("s_waitcnt vmcnt(4)\n\ts_barrier" ::: "memory");  // tile0 landed

  for (int kt = 0; kt < 16; ++kt) {
    int st = kt & 1;
    const unsigned short* bufA = ldsb + st * 16384;
    const unsigned short* bufB = bufA + 8192;

    short8 af[4][2], bf[2][2];
    #pragma unroll
    for (int kkb = 0; kkb < 2; ++kkb) {
      int kbyte = kkb * 64 + (lane >> 4) * 16;
      #pragma unroll
      for (int i = 0; i < 4; ++i) {
        int rowa = wm * 64 + i * 16 + (lane & 15);
        af[i][kkb] = *(const short8*)((const char*)bufA + rowa * 128 + (kbyte ^ ((rowa & 7) << 4)));
      }
      #pragma unroll
      for (int i = 0; i < 2; ++i) {
        int rowb = wn * 32 + i * 16 + (lane & 15);
        bf[i][kkb] = *(const short8*)((const char*)bufB + rowb * 128 + (kbyte ^ ((rowb & 7) << 4)));
      }
    }
    __asm__ volatile("s_waitcnt lgkmcnt(0)\n\ts_barrier" ::: "memory");
    if (kt < 14) {
      STAGE(kt + 2, st);
    } else {
      unsigned short* dead = ldsb + st * 16384;
      #pragma unroll
      for (int i = 0; i < 4; ++i) load16_to_lds(A + (size_t)r0 * 1024, &dead[i * 8]);
    }
    __builtin_amdgcn_s_setprio(1);
    #pragma unroll
    for (int kkb = 0; kkb < 2; ++kkb)
      #pragma unroll
      for (int i = 0; i < 4; ++i)
        #pragma unroll
        for (int jx = 0; jx < 2; ++jx)
          acc[i][jx] = __builtin_amdgcn_mfma_f32_16x16x32_bf16(af[i][kkb], bf[jx][kkb], acc[i][jx], 0, 0, 0);
    __builtin_amdgcn_s_setprio(0);
    __asm__ volatile("s_waitcnt vmcnt(4)\n\ts_barrier" ::: "memory");
  }
  __asm__ volatile("s_waitcnt vmcnt(0)" ::: "memory");  // drain LDS-DMA pre-retire

  int rbase = r0 + wm * 64 + (lane >> 4) * 4;
  int cbase = c0 + wn * 32 + (lane & 15);
  #pragma unroll
  for (int i = 0; i < 4; ++i)
    #pragma unroll
    for (int jx = 0; jx < 2; ++jx)
      #pragma unroll
      for (int q = 0; q < 4; ++q) {
        int R = rbase + i * 16 + q;
        int Crow = (R & 15) * 256 + (R >> 4);  // back to logits row c*256+t
        C[(size_t)Crow * 32000 + cbase + jx * 16] = acc[i][jx][q];
      }
}

// ---------- launch ----------
extern "C" void kernel_launch(void* const* d_in, const int* in_sizes, int n_in,
                              void* d_out, int out_size, void* d_ws, size_t ws_size,
                              hipStream_t stream) {
  const int* tok = (const int*)d_in[0];
  const float* emb = (const float*)d_in[1];
  const float* Wx = (const float*)d_in[2];
  const float* Wh = (const float*)d_in[3];
  const float* bias = (const float*)d_in[4];
  const float* lmW = (const float*)d_in[5];
  float* out = (float*)d_out;

  const size_t OFF_LMW = 0;                       // bf16 lm_W: 65,536,000
  const size_t OFF_XW = 65536000;                 // f32 xw:   16,777,216
  const size_t OFF_HALL = OFF_XW + 16777216;      // bf16 h_all: 8,388,608
  const size_t OFF_HCMB = OFF_HALL + 8388608;     // u64 hcomb: 262,144
  const size_t OFF_PROG = OFF_HCMB + 262144;      // u32 prog: 128
  const size_t NEED = OFF_PROG + 128;
  if (ws_size < NEED) {
    sentinel_kernel<<<1, 1, 0, stream>>>(out);
    return;
  }
  char* ws = (char*)d_ws;
  unsigned short* lmW_bf = (unsigned short*)(ws + OFF_LMW);
  float* xw = (float*)(ws + OFF_XW);
  unsigned short* h_all = (unsigned short*)(ws + OFF_HALL);
  unsigned long long* hcomb = (unsigned long long*)(ws + OFF_HCMB);
  unsigned int* prog = (unsigned int*)(ws + OFF_PROG);

  // tags + prog must restart at 0 EVERY call (graph replay!)
  hipMemsetAsync(ws + OFF_HCMB, 0, 262144 + 128, stream);
  xwcvt_kernel<<<1536, 256, 0, stream>>>(tok, emb, Wx, bias, xw, lmW, lmW_bf);
  recgemm_kernel<<<256 + 8000, 1024, 0, stream>>>(Wh, xw, tok, hcomb, h_all,
                                                  lmW_bf, out, prog);
}

// Round 13
// 985.642 us; speedup vs baseline: 3.2948x; 3.2948x over previous
//
#include <hip/hip_runtime.h>

#define PAD_IDX 0

typedef __attribute__((ext_vector_type(8))) short short8;
typedef __attribute__((ext_vector_type(4))) float f32x4;

// ---------- helpers ----------
__device__ __forceinline__ unsigned short f32_to_bf16_rne(float f) {
  unsigned int u = __builtin_bit_cast(unsigned int, f);
  u += 0x7FFFu + ((u >> 16) & 1u);
  return (unsigned short)(u >> 16);
}

__device__ __forceinline__ void load16_to_lds(const void* g, void* lds) {
  __builtin_amdgcn_global_load_lds(
      (const __attribute__((address_space(1))) unsigned int*)g,
      (__attribute__((address_space(3))) unsigned int*)lds,
      16, 0, 0);
}

// ---------- kernel 0: sentinel (only if ws too small) ----------
__global__ void sentinel_kernel(float* out) { out[0] = 1.0e6f; }

// ---------- kernel 1: merged xw + cvt (R10-proven) ----------
__global__ __launch_bounds__(256) void xwcvt_kernel(const int* __restrict__ tok,
                                                    const float* __restrict__ emb,
                                                    const float* __restrict__ Wx,
                                                    const float* __restrict__ bias,
                                                    float* __restrict__ xw,
                                                    const float* __restrict__ lmW,
                                                    unsigned short* __restrict__ lmW_bf) {
  int tid = threadIdx.x;
  if (blockIdx.x >= 1024) {
    const int n8 = 32000 * 1024 / 8;
    int stride = 512 * 256;
    for (int i = (blockIdx.x - 1024) * 256 + tid; i < n8; i += stride) {
      float4 a = ((const float4*)lmW)[2 * i];
      float4 b = ((const float4*)lmW)[2 * i + 1];
      ushort4 lo, hi;
      lo.x = f32_to_bf16_rne(a.x); lo.y = f32_to_bf16_rne(a.y);
      lo.z = f32_to_bf16_rne(a.z); lo.w = f32_to_bf16_rne(a.w);
      hi.x = f32_to_bf16_rne(b.x); hi.y = f32_to_bf16_rne(b.y);
      hi.z = f32_to_bf16_rne(b.z); hi.w = f32_to_bf16_rne(b.w);
      ((ushort4*)lmW_bf)[2 * i] = lo;
      ((ushort4*)lmW_bf)[2 * i + 1] = hi;
    }
    return;
  }
  __shared__ float At[32][68];
  __shared__ float Bt[32][68];
  __shared__ int stok[64];
  int tm = blockIdx.x & 63;
  int tn = blockIdx.x >> 6;
  int r0 = tm * 64, j0 = tn * 64;
  if (tid < 64) stok[tid] = tok[r0 + tid];
  int tx = tid & 15, ty = tid >> 4;
  float acc[4][4] = {};
  for (int kt = 0; kt < 512; kt += 32) {
    __syncthreads();
    #pragma unroll
    for (int ii = 0; ii < 2; ++ii) {
      int idx = tid * 2 + ii;
      int m = idx >> 3, fv = idx & 7;
      float4 va = *(const float4*)&emb[(size_t)stok[m] * 512 + kt + fv * 4];
      float4 vb = *(const float4*)&Wx[(size_t)(j0 + m) * 512 + kt + fv * 4];
      At[fv * 4 + 0][m] = va.x; At[fv * 4 + 1][m] = va.y;
      At[fv * 4 + 2][m] = va.z; At[fv * 4 + 3][m] = va.w;
      Bt[fv * 4 + 0][m] = vb.x; Bt[fv * 4 + 1][m] = vb.y;
      Bt[fv * 4 + 2][m] = vb.z; Bt[fv * 4 + 3][m] = vb.w;
    }
    __syncthreads();
    #pragma unroll
    for (int k = 0; k < 32; ++k) {
      float4 a4 = *(const float4*)&At[k][ty * 4];
      float4 b4 = *(const float4*)&Bt[k][tx * 4];
      float av[4] = {a4.x, a4.y, a4.z, a4.w};
      float bv[4] = {b4.x, b4.y, b4.z, b4.w};
      #pragma unroll
      for (int i = 0; i < 4; ++i)
        #pragma unroll
        for (int jj = 0; jj < 4; ++jj) acc[i][jj] = fmaf(av[i], bv[jj], acc[i][jj]);
    }
  }
  #pragma unroll
  for (int i = 0; i < 4; ++i) {
    size_t row = (size_t)(r0 + ty * 4 + i) * 1024 + j0 + tx * 4;
    #pragma unroll
    for (int jj = 0; jj < 4; ++jj)
      xw[row + jj] = acc[i][jj] + bias[j0 + tx * 4 + jj];
  }
}

// ---------- kernel 2: merged recurrence + overlapped GEMM (R13 fixes) ----------
// R12 post-mortem fixes, structure otherwise identical:
//  (1) gemm poll: ONLY tid==0 polls prog (acquire, s_sleep(8)) then s_barrier
//      — 256 pollers instead of 131072 (R5-style coherence-point flood killed rec).
//  (2) rec h_all: paired-u32 AGENT (sc1) stores — coherent-point-visible at
//      vmcnt-retire — so prog release is s_waitcnt vmcnt(0) + RELAXED fetch_add.
//      NO threadfence in the rec loop (the buffer_wbl2 storm was evicting L2).
__global__ __launch_bounds__(1024) void recgemm_kernel(const float* __restrict__ Wh,
                                                       const float* __restrict__ xw,
                                                       const int* __restrict__ tok,
                                                       unsigned long long* hcomb,  // [2][16][1024]
                                                       unsigned short* h_all,      // [256*16][1024] R=t*16+c
                                                       const unsigned short* __restrict__ Bm,  // lmW_bf
                                                       float* __restrict__ C,
                                                       unsigned int* prog) {       // [32]
  __shared__ __align__(16) char smem[65536];
  int bid = blockIdx.x;
  int tid = threadIdx.x;

  if (bid < 256) {
    // ================= REC role =================
    int c = bid & 15;
    int g = bid >> 4;
    int w = tid >> 6;
    int l = tid & 63;
    int j = g * 64 + l;

    const float* wb = Wh + (size_t)j * 1024 + w * 64;
#define LDW(i) f32x4 w##i = *(const f32x4*)(wb + i * 4);
    LDW(0) LDW(1) LDW(2) LDW(3) LDW(4) LDW(5) LDW(6) LDW(7)
    LDW(8) LDW(9) LDW(10) LDW(11) LDW(12) LDW(13) LDW(14) LDW(15)
#undef LDW

    float* hs = (float*)smem;            // [16][64]
    float* pbuf = hs + 16 * 64;          // [16][64]
    unsigned long long* hc0 = hcomb + (size_t)c * 1024;
    unsigned long long* hc1 = hcomb + 16 * 1024 + (size_t)c * 1024;
    unsigned int* h32 = (unsigned int*)h_all;
    bool writer = (w == 0);
    float prevh = 0.f;

    for (int t = 0; t < 256; ++t) {
      float xv = 0.f;
      int tkn = 1;
      if (writer) {
        xv = xw[((size_t)c * 256 + t) * 1024 + j];
        tkn = tok[c * 256 + t];
      }
      unsigned long long* src = ((t & 1) ? hc1 : hc0) + tid;
      unsigned long long v;
      int guard = 0;
      do {
        v = __hip_atomic_load(src, __ATOMIC_RELAXED, __HIP_MEMORY_SCOPE_AGENT);
        if ((unsigned int)(v >> 32) == (unsigned int)t) break;
        __builtin_amdgcn_s_sleep(1);
      } while (++guard < (1 << 20));  // fail loud, not hung
      hs[w * 64 + l] = __builtin_bit_cast(float, (unsigned int)v);
      __asm__ volatile("s_waitcnt lgkmcnt(0)" ::: "memory");  // wave-local share

      const float* hp = hs + w * 64;
      f32x4 a0 = {0.f, 0.f, 0.f, 0.f}, a1 = a0, a2 = a0, a3 = a0;
#define FMAI(i, acc) { f32x4 h4 = *(const f32x4*)(hp + i * 4); acc += w##i * h4; }
      FMAI(0, a0) FMAI(1, a1) FMAI(2, a2) FMAI(3, a3)
      FMAI(4, a0) FMAI(5, a1) FMAI(6, a2) FMAI(7, a3)
      FMAI(8, a0) FMAI(9, a1) FMAI(10, a2) FMAI(11, a3)
      FMAI(12, a0) FMAI(13, a1) FMAI(14, a2) FMAI(15, a3)
#undef FMAI
      f32x4 aa = (a0 + a1) + (a2 + a3);
      pbuf[w * 64 + l] = (aa[0] + aa[1]) + (aa[2] + aa[3]);
      __asm__ volatile("s_waitcnt lgkmcnt(0)\n\ts_barrier" ::: "memory");

      if (writer) {
        float s = 0.f;
        #pragma unroll
        for (int q = 0; q < 16; ++q) s += pbuf[q * 64 + l];
        float hnew;
        if (tkn != PAD_IDX) {
          float pre = xv + s;
          float e = __builtin_amdgcn_exp2f(pre * 2.8853900817779268f);  // exp(2x)
          hnew = 1.0f - 2.0f / (e + 1.0f);                              // tanh(x)
        } else {
          hnew = prevh;
        }
        prevh = hnew;
        unsigned long long pv =
            ((unsigned long long)(unsigned int)(t + 1) << 32) |
            (unsigned long long)__builtin_bit_cast(unsigned int, hnew);
        __hip_atomic_store((((t + 1) & 1) ? hc1 : hc0) + j, pv,
                           __ATOMIC_RELAXED, __HIP_MEMORY_SCOPE_AGENT);
        // paired-u32 sc1 store: coherent-point-visible once vmcnt retires
        unsigned int hb = f32_to_bf16_rne(hnew);
        unsigned int partner = (unsigned int)__shfl_xor((int)hb, 1);
        if (!(l & 1)) {
          unsigned int pairv = hb | (partner << 16);
          __hip_atomic_store(h32 + ((size_t)t * 16 + c) * 512 + g * 32 + (l >> 1),
                             pairv, __ATOMIC_RELAXED, __HIP_MEMORY_SCOPE_AGENT);
        }
        if ((t & 7) == 7) {
          __asm__ volatile("s_waitcnt vmcnt(0)" ::: "memory");  // h_all stores done
          if (tid == 0)
            __hip_atomic_fetch_add(prog + (t >> 3), 1u,
                                   __ATOMIC_RELAXED, __HIP_MEMORY_SCOPE_AGENT);
        }
      }
    }
    return;
  }

  // ================= GEMM role =================
  if (tid >= 512) return;  // exits before any barrier; 8 live waves remain
  int gb = bid - 256;
  int mtile = gb / 250, ntile = gb - mtile * 250;
  int r0 = mtile * 128, c0 = ntile * 128;
  int lane = tid & 63, wave = tid >> 6;
  int wm = wave >> 2, wn = wave & 3;  // 2M x 4N; per-wave 64x32

  if (tid == 0) {  // SINGLE poller per block (fix #1); acquire -> cache inv
    long guard = 0;
    while (__hip_atomic_load(prog + mtile, __ATOMIC_ACQUIRE, __HIP_MEMORY_SCOPE_AGENT) < 256u) {
      __builtin_amdgcn_s_sleep(8);
      if (++guard > (1L << 22)) break;  // fail loud, not hung
    }
  }
  __asm__ volatile("s_barrier" ::: "memory");

  unsigned short* ldsb = (unsigned short*)smem;
  const unsigned short* A = h_all;

  auto STAGE = [&](int kt, int st) {
    unsigned short* bufA = ldsb + st * 16384;
    unsigned short* bufB = bufA + 8192;
    #pragma unroll
    for (int i = 0; i < 2; ++i) {
      int slot = i * 512 + tid;        // 0..1023 = 128 rows x 8 granules
      int row = slot >> 3, sg = slot & 7;
      int kg = sg ^ (row & 7);
      const unsigned short* ga = A + (size_t)(r0 + row) * 1024 + kt * 64 + kg * 8;
      load16_to_lds(ga, &bufA[(i * 512 + wave * 64) * 8]);
    }
    #pragma unroll
    for (int i = 0; i < 2; ++i) {
      int slot = i * 512 + tid;
      int row = slot >> 3, sg = slot & 7;
      int kg = sg ^ (row & 7);
      const unsigned short* gb2 = Bm + (size_t)(c0 + row) * 1024 + kt * 64 + kg * 8;
      load16_to_lds(gb2, &bufB[(i * 512 + wave * 64) * 8]);
    }
  };

  f32x4 zero = {0.f, 0.f, 0.f, 0.f};
  f32x4 acc[4][2];
  #pragma unroll
  for (int i = 0; i < 4; ++i)
    #pragma unroll
    for (int jx = 0; jx < 2; ++jx) acc[i][jx] = zero;

  STAGE(0, 0);
  STAGE(1, 1);
  __asm__ volatile("s_waitcnt vmcnt(4)\n\ts_barrier" ::: "memory");  // tile0 landed

  for (int kt = 0; kt < 16; ++kt) {
    int st = kt & 1;
    const unsigned short* bufA = ldsb + st * 16384;
    const unsigned short* bufB = bufA + 8192;

    short8 af[4][2], bf[2][2];
    #pragma unroll
    for (int kkb = 0; kkb < 2; ++kkb) {
      int kbyte = kkb * 64 + (lane >> 4) * 16;
      #pragma unroll
      for (int i = 0; i < 4; ++i) {
        int rowa = wm * 64 + i * 16 + (lane & 15);
        af[i][kkb] = *(const short8*)((const char*)bufA + rowa * 128 + (kbyte ^ ((rowa & 7) << 4)));
      }
      #pragma unroll
      for (int i = 0; i < 2; ++i) {
        int rowb = wn * 32 + i * 16 + (lane & 15);
        bf[i][kkb] = *(const short8*)((const char*)bufB + rowb * 128 + (kbyte ^ ((rowb & 7) << 4)));
      }
    }
    __asm__ volatile("s_waitcnt lgkmcnt(0)\n\ts_barrier" ::: "memory");
    if (kt < 14) {
      STAGE(kt + 2, st);
    } else {
      unsigned short* dead = ldsb + st * 16384;
      #pragma unroll
      for (int i = 0; i < 4; ++i) load16_to_lds(A + (size_t)r0 * 1024, &dead[i * 8]);
    }
    __builtin_amdgcn_s_setprio(1);
    #pragma unroll
    for (int kkb = 0; kkb < 2; ++kkb)
      #pragma unroll
      for (int i = 0; i < 4; ++i)
        #pragma unroll
        for (int jx = 0; jx < 2; ++jx)
          acc[i][jx] = __builtin_amdgcn_mfma_f32_16x16x32_bf16(af[i][kkb], bf[jx][kkb], acc[i][jx], 0, 0, 0);
    __builtin_amdgcn_s_setprio(0);
    __asm__ volatile("s_waitcnt vmcnt(4)\n\ts_barrier" ::: "memory");
  }
  __asm__ volatile("s_waitcnt vmcnt(0)" ::: "memory");  // drain LDS-DMA pre-retire

  int rbase = r0 + wm * 64 + (lane >> 4) * 4;
  int cbase = c0 + wn * 32 + (lane & 15);
  #pragma unroll
  for (int i = 0; i < 4; ++i)
    #pragma unroll
    for (int jx = 0; jx < 2; ++jx)
      #pragma unroll
      for (int q = 0; q < 4; ++q) {
        int R = rbase + i * 16 + q;
        int Crow = (R & 15) * 256 + (R >> 4);  // back to logits row c*256+t
        C[(size_t)Crow * 32000 + cbase + jx * 16] = acc[i][jx][q];
      }
}

// ---------- launch ----------
extern "C" void kernel_launch(void* const* d_in, const int* in_sizes, int n_in,
                              void* d_out, int out_size, void* d_ws, size_t ws_size,
                              hipStream_t stream) {
  const int* tok = (const int*)d_in[0];
  const float* emb = (const float*)d_in[1];
  const float* Wx = (const float*)d_in[2];
  const float* Wh = (const float*)d_in[3];
  const float* bias = (const float*)d_in[4];
  const float* lmW = (const float*)d_in[5];
  float* out = (float*)d_out;

  const size_t OFF_LMW = 0;                       // bf16 lm_W: 65,536,000
  const size_t OFF_XW = 65536000;                 // f32 xw:   16,777,216
  const size_t OFF_HALL = OFF_XW + 16777216;      // bf16 h_all: 8,388,608
  const size_t OFF_HCMB = OFF_HALL + 8388608;     // u64 hcomb: 262,144
  const size_t OFF_PROG = OFF_HCMB + 262144;      // u32 prog: 128
  const size_t NEED = OFF_PROG + 128;
  if (ws_size < NEED) {
    sentinel_kernel<<<1, 1, 0, stream>>>(out);
    return;
  }
  char* ws = (char*)d_ws;
  unsigned short* lmW_bf = (unsigned short*)(ws + OFF_LMW);
  float* xw = (float*)(ws + OFF_XW);
  unsigned short* h_all = (unsigned short*)(ws + OFF_HALL);
  unsigned long long* hcomb = (unsigned long long*)(ws + OFF_HCMB);
  unsigned int* prog = (unsigned int*)(ws + OFF_PROG);

  // tags + prog must restart at 0 EVERY call (graph replay!)
  hipMemsetAsync(ws + OFF_HCMB, 0, 262144 + 128, stream);
  xwcvt_kernel<<<1536, 256, 0, stream>>>(tok, emb, Wx, bias, xw, lmW, lmW_bf);
  recgemm_kernel<<<256 + 8000, 1024, 0, stream>>>(Wh, xw, tok, hcomb, h_all,
                                                  lmW_bf, out, prog);
}

// Round 14
// 869.336 us; speedup vs baseline: 3.7356x; 1.1338x over previous
//
#include <hip/hip_runtime.h>

#define PAD_IDX 0

typedef __attribute__((ext_vector_type(8))) short short8;
typedef __attribute__((ext_vector_type(4))) float f32x4;

// ---------- helpers ----------
__device__ __forceinline__ unsigned short f32_to_bf16_rne(float f) {
  unsigned int u = __builtin_bit_cast(unsigned int, f);
  u += 0x7FFFu + ((u >> 16) & 1u);
  return (unsigned short)(u >> 16);
}

__device__ __forceinline__ void load16_to_lds(const void* g, void* lds) {
  __builtin_amdgcn_global_load_lds(
      (const __attribute__((address_space(1))) unsigned int*)g,
      (__attribute__((address_space(3))) unsigned int*)lds,
      16, 0, 0);
}

// ---------- kernel 0: sentinel (only if ws too small) ----------
__global__ void sentinel_kernel(float* out) { out[0] = 1.0e6f; }

// ---------- kernel 1: merged xw + cvt (R10-proven: cvt hides under xw) ----------
__global__ __launch_bounds__(256) void xwcvt_kernel(const int* __restrict__ tok,
                                                    const float* __restrict__ emb,
                                                    const float* __restrict__ Wx,
                                                    const float* __restrict__ bias,
                                                    float* __restrict__ xw,
                                                    const float* __restrict__ lmW,
                                                    unsigned short* __restrict__ lmW_bf) {
  int tid = threadIdx.x;
  if (blockIdx.x >= 1024) {
    const int n8 = 32000 * 1024 / 8;
    int stride = 512 * 256;
    for (int i = (blockIdx.x - 1024) * 256 + tid; i < n8; i += stride) {
      float4 a = ((const float4*)lmW)[2 * i];
      float4 b = ((const float4*)lmW)[2 * i + 1];
      ushort4 lo, hi;
      lo.x = f32_to_bf16_rne(a.x); lo.y = f32_to_bf16_rne(a.y);
      lo.z = f32_to_bf16_rne(a.z); lo.w = f32_to_bf16_rne(a.w);
      hi.x = f32_to_bf16_rne(b.x); hi.y = f32_to_bf16_rne(b.y);
      hi.z = f32_to_bf16_rne(b.z); hi.w = f32_to_bf16_rne(b.w);
      ((ushort4*)lmW_bf)[2 * i] = lo;
      ((ushort4*)lmW_bf)[2 * i + 1] = hi;
    }
    return;
  }
  __shared__ float At[32][68];
  __shared__ float Bt[32][68];
  __shared__ int stok[64];
  int tm = blockIdx.x & 63;
  int tn = blockIdx.x >> 6;
  int r0 = tm * 64, j0 = tn * 64;
  if (tid < 64) stok[tid] = tok[r0 + tid];
  int tx = tid & 15, ty = tid >> 4;
  float acc[4][4] = {};
  for (int kt = 0; kt < 512; kt += 32) {
    __syncthreads();
    #pragma unroll
    for (int ii = 0; ii < 2; ++ii) {
      int idx = tid * 2 + ii;
      int m = idx >> 3, fv = idx & 7;
      float4 va = *(const float4*)&emb[(size_t)stok[m] * 512 + kt + fv * 4];
      float4 vb = *(const float4*)&Wx[(size_t)(j0 + m) * 512 + kt + fv * 4];
      At[fv * 4 + 0][m] = va.x; At[fv * 4 + 1][m] = va.y;
      At[fv * 4 + 2][m] = va.z; At[fv * 4 + 3][m] = va.w;
      Bt[fv * 4 + 0][m] = vb.x; Bt[fv * 4 + 1][m] = vb.y;
      Bt[fv * 4 + 2][m] = vb.z; Bt[fv * 4 + 3][m] = vb.w;
    }
    __syncthreads();
    #pragma unroll
    for (int k = 0; k < 32; ++k) {
      float4 a4 = *(const float4*)&At[k][ty * 4];
      float4 b4 = *(const float4*)&Bt[k][tx * 4];
      float av[4] = {a4.x, a4.y, a4.z, a4.w};
      float bv[4] = {b4.x, b4.y, b4.z, b4.w};
      #pragma unroll
      for (int i = 0; i < 4; ++i)
        #pragma unroll
        for (int jj = 0; jj < 4; ++jj) acc[i][jj] = fmaf(av[i], bv[jj], acc[i][jj]);
    }
  }
  #pragma unroll
  for (int i = 0; i < 4; ++i) {
    size_t row = (size_t)(r0 + ty * 4 + i) * 1024 + j0 + tx * 4;
    #pragma unroll
    for (int jj = 0; jj < 4; ++jj)
      xw[row + jj] = acc[i][jj] + bias[j0 + tx * 4 + jj];
  }
}

// ---------- kernel 3: recurrence (exact R10 structure — proven 456 us) ----------
// 256 WGs x 1024 thr, 1 WG/CU. chain c = blk&15 (XCD-local under round-robin),
// wg g = blk>>4 owns rows g*64..+63. Wave w = k-slice [w*64,+64); lane l = row.
// Sync: fused data+tag u64 poll (s_sleep), wave-local LDS share (no barrier),
// ONE barrier, writer serial-16 reduce, relaxed agent store. prevh register
// for the pad path. Serial with gemm ON PURPOSE: R12/R13 proved concurrent
// gemm L3 traffic taxes this latency chain more than the overlap pays.
__global__ __launch_bounds__(1024, 4) void rec_kernel(const float* __restrict__ Wh,
                                                      const float* __restrict__ xw,
                                                      const int* __restrict__ tok,
                                                      unsigned long long* hcomb,  // [2][16][1024]
                                                      unsigned short* __restrict__ h_all) {
  int c = blockIdx.x & 15;
  int g = blockIdx.x >> 4;
  int tid = threadIdx.x;
  int w = tid >> 6;
  int l = tid & 63;
  int j = g * 64 + l;

  const float* wb = Wh + (size_t)j * 1024 + w * 64;
#define LDW(i) f32x4 w##i = *(const f32x4*)(wb + i * 4);
  LDW(0) LDW(1) LDW(2) LDW(3) LDW(4) LDW(5) LDW(6) LDW(7)
  LDW(8) LDW(9) LDW(10) LDW(11) LDW(12) LDW(13) LDW(14) LDW(15)
#undef LDW

  __shared__ float hs[16][64];
  __shared__ float pbuf[16][64];
  unsigned long long* hc0 = hcomb + (size_t)c * 1024;
  unsigned long long* hc1 = hcomb + 16 * 1024 + (size_t)c * 1024;
  bool writer = (w == 0);
  float prevh = 0.f;

  for (int t = 0; t < 256; ++t) {
    float xv = 0.f;
    int tkn = 1;
    if (writer) {
      xv = xw[((size_t)c * 256 + t) * 1024 + j];
      tkn = tok[c * 256 + t];
    }
    unsigned long long* src = ((t & 1) ? hc1 : hc0) + tid;
    unsigned long long v;
    int guard = 0;
    do {
      v = __hip_atomic_load(src, __ATOMIC_RELAXED, __HIP_MEMORY_SCOPE_AGENT);
      if ((unsigned int)(v >> 32) == (unsigned int)t) break;
      __builtin_amdgcn_s_sleep(1);
    } while (++guard < (1 << 20));  // fail loud, not hung
    hs[w][l] = __builtin_bit_cast(float, (unsigned int)v);
    __asm__ volatile("s_waitcnt lgkmcnt(0)" ::: "memory");  // wave-local share

    const float* hp = &hs[w][0];
    f32x4 a0 = {0.f, 0.f, 0.f, 0.f}, a1 = a0, a2 = a0, a3 = a0;
#define FMAI(i, acc) { f32x4 h4 = *(const f32x4*)(hp + i * 4); acc += w##i * h4; }
    FMAI(0, a0) FMAI(1, a1) FMAI(2, a2) FMAI(3, a3)
    FMAI(4, a0) FMAI(5, a1) FMAI(6, a2) FMAI(7, a3)
    FMAI(8, a0) FMAI(9, a1) FMAI(10, a2) FMAI(11, a3)
    FMAI(12, a0) FMAI(13, a1) FMAI(14, a2) FMAI(15, a3)
#undef FMAI
    f32x4 aa = (a0 + a1) + (a2 + a3);
    pbuf[w][l] = (aa[0] + aa[1]) + (aa[2] + aa[3]);
    __asm__ volatile("s_waitcnt lgkmcnt(0)\n\ts_barrier" ::: "memory");

    if (writer) {
      float s = 0.f;
      #pragma unroll
      for (int q = 0; q < 16; ++q) s += pbuf[q][l];
      float hnew;
      if (tkn != PAD_IDX) {
        float pre = xv + s;
        float e = __builtin_amdgcn_exp2f(pre * 2.8853900817779268f);  // exp(2x)
        hnew = 1.0f - 2.0f / (e + 1.0f);                              // tanh(x)
      } else {
        hnew = prevh;  // register: race-free old h of own row
      }
      prevh = hnew;
      unsigned long long pv =
          ((unsigned long long)(unsigned int)(t + 1) << 32) |
          (unsigned long long)__builtin_bit_cast(unsigned int, hnew);
      __hip_atomic_store((((t + 1) & 1) ? hc1 : hc0) + j, pv,
                         __ATOMIC_RELAXED, __HIP_MEMORY_SCOPE_AGENT);
      h_all[((size_t)c * 256 + t) * 1024 + j] = f32_to_bf16_rne(hnew);
    }
  }
}

// ---------- kernel 4: logits = h_all(bf16) @ lm_W(bf16)^T, f32 out ----------
// R11-proven: BM=256 BN=256 BK=64, 512 thr (8 waves 2Mx4N), 2 LDS stages,
// counted vmcnt(8), cheap tail dead-stage, final vmcnt(0) drain.
// L3 remap (confirmed -32us): XCD x owns Mtiles {2x,2x+1} (A L2-resident);
// tm alternates fastest so each B panel is fetched once per XCD.
__global__ __launch_bounds__(512) void gemm_kernel(const unsigned short* __restrict__ A,
                                                   const unsigned short* __restrict__ B,
                                                   float* __restrict__ C) {
  __shared__ unsigned short lds[2 * 32768];
  int tid = threadIdx.x;
  int lane = tid & 63, wave = tid >> 6;
  int bid = blockIdx.x;
  int x = bid & 7;               // XCD under round-robin dispatch
  int r = bid >> 3;              // 0..249 within XCD
  int tm = 2 * x + (r & 1);      // XCD owns 2 A-panels; tm fastest
  int tn = r >> 1;               // B panel reused by 2 consecutive WGs
  int r0 = tm * 256, c0 = tn * 256;
  int wm = wave >> 2, wn = wave & 3;  // 2M x 4N

  auto STAGE = [&](int kt, int st) {
    unsigned short* bufA = (unsigned short*)lds + st * 32768;
    unsigned short* bufB = bufA + 16384;
    #pragma unroll
    for (int i = 0; i < 4; ++i) {
      int slot = i * 512 + tid;
      int row = slot >> 3, sg = slot & 7;
      int kg = sg ^ (row & 7);
      const unsigned short* ga = A + (size_t)(r0 + row) * 1024 + kt * 64 + kg * 8;
      load16_to_lds(ga, &bufA[(i * 512 + wave * 64) * 8]);
    }
    #pragma unroll
    for (int i = 0; i < 4; ++i) {
      int slot = i * 512 + tid;
      int row = slot >> 3, sg = slot & 7;
      int kg = sg ^ (row & 7);
      const unsigned short* gb = B + (size_t)(c0 + row) * 1024 + kt * 64 + kg * 8;
      load16_to_lds(gb, &bufB[(i * 512 + wave * 64) * 8]);
    }
  };

  f32x4 zero = {0.f, 0.f, 0.f, 0.f};
  f32x4 acc[8][4];
  #pragma unroll
  for (int i = 0; i < 8; ++i)
    #pragma unroll
    for (int jx = 0; jx < 4; ++jx) acc[i][jx] = zero;

  STAGE(0, 0);
  STAGE(1, 1);
  __asm__ volatile("s_waitcnt vmcnt(8)\n\ts_barrier" ::: "memory");  // tile0 landed

  for (int kt = 0; kt < 16; ++kt) {
    int st = kt & 1;
    const unsigned short* bufA = (const unsigned short*)lds + st * 32768;
    const unsigned short* bufB = bufA + 16384;

    short8 af[8][2], bf[4][2];
    #pragma unroll
    for (int kkb = 0; kkb < 2; ++kkb) {
      int kbyte = kkb * 64 + (lane >> 4) * 16;
      #pragma unroll
      for (int i = 0; i < 8; ++i) {
        int rowa = wm * 128 + i * 16 + (lane & 15);
        af[i][kkb] = *(const short8*)((const char*)bufA + rowa * 128 + (kbyte ^ ((rowa & 7) << 4)));
      }
      #pragma unroll
      for (int i = 0; i < 4; ++i) {
        int rowb = wn * 64 + i * 16 + (lane & 15);
        bf[i][kkb] = *(const short8*)((const char*)bufB + rowb * 128 + (kbyte ^ ((rowb & 7) << 4)));
      }
    }
    // all waves' ds_reads of this buffer must retire before restaging into it
    __asm__ volatile("s_waitcnt lgkmcnt(0)\n\ts_barrier" ::: "memory");
    if (kt < 14) {
      STAGE(kt + 2, st);
    } else {
      // dead-stage: 8 loads of one hot 16B line into the retired buffer (vmcnt math)
      unsigned short* dead = (unsigned short*)lds + st * 32768;
      #pragma unroll
      for (int i = 0; i < 8; ++i) load16_to_lds(A + (size_t)r0 * 1024, &dead[i * 8]);
    }
    __builtin_amdgcn_s_setprio(1);
    #pragma unroll
    for (int kkb = 0; kkb < 2; ++kkb)
      #pragma unroll
      for (int i = 0; i < 8; ++i)
        #pragma unroll
        for (int jx = 0; jx < 4; ++jx)
          acc[i][jx] = __builtin_amdgcn_mfma_f32_16x16x32_bf16(af[i][kkb], bf[jx][kkb], acc[i][jx], 0, 0, 0);
    __builtin_amdgcn_s_setprio(0);
    __asm__ volatile("s_waitcnt vmcnt(8)\n\ts_barrier" ::: "memory");
  }
  // drain ALL outstanding LDS-DMA before this WG can retire (LDS reassignment!)
  __asm__ volatile("s_waitcnt vmcnt(0)" ::: "memory");

  int rbase = r0 + wm * 128 + (lane >> 4) * 4;
  int cbase = c0 + wn * 64 + (lane & 15);
  #pragma unroll
  for (int i = 0; i < 8; ++i)
    #pragma unroll
    for (int jx = 0; jx < 4; ++jx)
      #pragma unroll
      for (int q = 0; q < 4; ++q)
        C[(size_t)(rbase + i * 16 + q) * 32000 + cbase + jx * 16] = acc[i][jx][q];
}

// ---------- launch ----------
extern "C" void kernel_launch(void* const* d_in, const int* in_sizes, int n_in,
                              void* d_out, int out_size, void* d_ws, size_t ws_size,
                              hipStream_t stream) {
  const int* tok = (const int*)d_in[0];
  const float* emb = (const float*)d_in[1];
  const float* Wx = (const float*)d_in[2];
  const float* Wh = (const float*)d_in[3];
  const float* bias = (const float*)d_in[4];
  const float* lmW = (const float*)d_in[5];
  float* out = (float*)d_out;

  const size_t OFF_LMW = 0;                       // bf16 lm_W: 65,536,000
  const size_t OFF_XW = 65536000;                 // f32 xw:   16,777,216
  const size_t OFF_HALL = OFF_XW + 16777216;      // bf16 h_all: 8,388,608
  const size_t OFF_HCMB = OFF_HALL + 8388608;     // u64 hcomb: 262,144
  const size_t NEED = OFF_HCMB + 262144;
  if (ws_size < NEED) {
    sentinel_kernel<<<1, 1, 0, stream>>>(out);
    return;
  }
  char* ws = (char*)d_ws;
  unsigned short* lmW_bf = (unsigned short*)(ws + OFF_LMW);
  float* xw = (float*)(ws + OFF_XW);
  unsigned short* h_all = (unsigned short*)(ws + OFF_HALL);
  unsigned long long* hcomb = (unsigned long long*)(ws + OFF_HCMB);

  // tags must restart at 0 EVERY call (graph replay!)
  hipMemsetAsync(ws + OFF_HCMB, 0, 262144, stream);
  xwcvt_kernel<<<1536, 256, 0, stream>>>(tok, emb, Wx, bias, xw, lmW, lmW_bf);
  rec_kernel<<<256, 1024, 0, stream>>>(Wh, xw, tok, hcomb, h_all);
  gemm_kernel<<<2000, 512, 0, stream>>>(h_all, lmW_bf, out);
}

// Round 15
// 868.426 us; speedup vs baseline: 3.7395x; 1.0010x over previous
//
#include <hip/hip_runtime.h>

#define PAD_IDX 0

typedef __attribute__((ext_vector_type(8))) short short8;
typedef __attribute__((ext_vector_type(4))) float f32x4;

// ---------- helpers ----------
__device__ __forceinline__ unsigned short f32_to_bf16_rne(float f) {
  unsigned int u = __builtin_bit_cast(unsigned int, f);
  u += 0x7FFFu + ((u >> 16) & 1u);
  return (unsigned short)(u >> 16);
}

__device__ __forceinline__ void load16_to_lds(const void* g, void* lds) {
  __builtin_amdgcn_global_load_lds(
      (const __attribute__((address_space(1))) unsigned int*)g,
      (__attribute__((address_space(3))) unsigned int*)lds,
      16, 0, 0);
}

// ---------- kernel 0: sentinel (only if ws too small) ----------
__global__ void sentinel_kernel(float* out) { out[0] = 1.0e6f; }

// ---------- kernel 1: merged xw + cvt (R10-proven: cvt hides under xw) ----------
__global__ __launch_bounds__(256) void xwcvt_kernel(const int* __restrict__ tok,
                                                    const float* __restrict__ emb,
                                                    const float* __restrict__ Wx,
                                                    const float* __restrict__ bias,
                                                    float* __restrict__ xw,
                                                    const float* __restrict__ lmW,
                                                    unsigned short* __restrict__ lmW_bf) {
  int tid = threadIdx.x;
  if (blockIdx.x >= 1024) {
    const int n8 = 32000 * 1024 / 8;
    int stride = 512 * 256;
    for (int i = (blockIdx.x - 1024) * 256 + tid; i < n8; i += stride) {
      float4 a = ((const float4*)lmW)[2 * i];
      float4 b = ((const float4*)lmW)[2 * i + 1];
      ushort4 lo, hi;
      lo.x = f32_to_bf16_rne(a.x); lo.y = f32_to_bf16_rne(a.y);
      lo.z = f32_to_bf16_rne(a.z); lo.w = f32_to_bf16_rne(a.w);
      hi.x = f32_to_bf16_rne(b.x); hi.y = f32_to_bf16_rne(b.y);
      hi.z = f32_to_bf16_rne(b.z); hi.w = f32_to_bf16_rne(b.w);
      ((ushort4*)lmW_bf)[2 * i] = lo;
      ((ushort4*)lmW_bf)[2 * i + 1] = hi;
    }
    return;
  }
  __shared__ float At[32][68];
  __shared__ float Bt[32][68];
  __shared__ int stok[64];
  int tm = blockIdx.x & 63;
  int tn = blockIdx.x >> 6;
  int r0 = tm * 64, j0 = tn * 64;
  if (tid < 64) stok[tid] = tok[r0 + tid];
  int tx = tid & 15, ty = tid >> 4;
  float acc[4][4] = {};
  for (int kt = 0; kt < 512; kt += 32) {
    __syncthreads();
    #pragma unroll
    for (int ii = 0; ii < 2; ++ii) {
      int idx = tid * 2 + ii;
      int m = idx >> 3, fv = idx & 7;
      float4 va = *(const float4*)&emb[(size_t)stok[m] * 512 + kt + fv * 4];
      float4 vb = *(const float4*)&Wx[(size_t)(j0 + m) * 512 + kt + fv * 4];
      At[fv * 4 + 0][m] = va.x; At[fv * 4 + 1][m] = va.y;
      At[fv * 4 + 2][m] = va.z; At[fv * 4 + 3][m] = va.w;
      Bt[fv * 4 + 0][m] = vb.x; Bt[fv * 4 + 1][m] = vb.y;
      Bt[fv * 4 + 2][m] = vb.z; Bt[fv * 4 + 3][m] = vb.w;
    }
    __syncthreads();
    #pragma unroll
    for (int k = 0; k < 32; ++k) {
      float4 a4 = *(const float4*)&At[k][ty * 4];
      float4 b4 = *(const float4*)&Bt[k][tx * 4];
      float av[4] = {a4.x, a4.y, a4.z, a4.w};
      float bv[4] = {b4.x, b4.y, b4.z, b4.w};
      #pragma unroll
      for (int i = 0; i < 4; ++i)
        #pragma unroll
        for (int jj = 0; jj < 4; ++jj) acc[i][jj] = fmaf(av[i], bv[jj], acc[i][jj]);
    }
  }
  #pragma unroll
  for (int i = 0; i < 4; ++i) {
    size_t row = (size_t)(r0 + ty * 4 + i) * 1024 + j0 + tx * 4;
    #pragma unroll
    for (int jj = 0; jj < 4; ++jj)
      xw[row + jj] = acc[i][jj] + bias[j0 + tx * 4 + jj];
  }
}

// ---------- kernel 3: recurrence (exact R10 structure — proven 456 us x3) ----------
__global__ __launch_bounds__(1024, 4) void rec_kernel(const float* __restrict__ Wh,
                                                      const float* __restrict__ xw,
                                                      const int* __restrict__ tok,
                                                      unsigned long long* hcomb,  // [2][16][1024]
                                                      unsigned short* __restrict__ h_all) {
  int c = blockIdx.x & 15;
  int g = blockIdx.x >> 4;
  int tid = threadIdx.x;
  int w = tid >> 6;
  int l = tid & 63;
  int j = g * 64 + l;

  const float* wb = Wh + (size_t)j * 1024 + w * 64;
#define LDW(i) f32x4 w##i = *(const f32x4*)(wb + i * 4);
  LDW(0) LDW(1) LDW(2) LDW(3) LDW(4) LDW(5) LDW(6) LDW(7)
  LDW(8) LDW(9) LDW(10) LDW(11) LDW(12) LDW(13) LDW(14) LDW(15)
#undef LDW

  __shared__ float hs[16][64];
  __shared__ float pbuf[16][64];
  unsigned long long* hc0 = hcomb + (size_t)c * 1024;
  unsigned long long* hc1 = hcomb + 16 * 1024 + (size_t)c * 1024;
  bool writer = (w == 0);
  float prevh = 0.f;

  for (int t = 0; t < 256; ++t) {
    float xv = 0.f;
    int tkn = 1;
    if (writer) {
      xv = xw[((size_t)c * 256 + t) * 1024 + j];
      tkn = tok[c * 256 + t];
    }
    unsigned long long* src = ((t & 1) ? hc1 : hc0) + tid;
    unsigned long long v;
    int guard = 0;
    do {
      v = __hip_atomic_load(src, __ATOMIC_RELAXED, __HIP_MEMORY_SCOPE_AGENT);
      if ((unsigned int)(v >> 32) == (unsigned int)t) break;
      __builtin_amdgcn_s_sleep(1);
    } while (++guard < (1 << 20));  // fail loud, not hung
    hs[w][l] = __builtin_bit_cast(float, (unsigned int)v);
    __asm__ volatile("s_waitcnt lgkmcnt(0)" ::: "memory");  // wave-local share

    const float* hp = &hs[w][0];
    f32x4 a0 = {0.f, 0.f, 0.f, 0.f}, a1 = a0, a2 = a0, a3 = a0;
#define FMAI(i, acc) { f32x4 h4 = *(const f32x4*)(hp + i * 4); acc += w##i * h4; }
    FMAI(0, a0) FMAI(1, a1) FMAI(2, a2) FMAI(3, a3)
    FMAI(4, a0) FMAI(5, a1) FMAI(6, a2) FMAI(7, a3)
    FMAI(8, a0) FMAI(9, a1) FMAI(10, a2) FMAI(11, a3)
    FMAI(12, a0) FMAI(13, a1) FMAI(14, a2) FMAI(15, a3)
#undef FMAI
    f32x4 aa = (a0 + a1) + (a2 + a3);
    pbuf[w][l] = (aa[0] + aa[1]) + (aa[2] + aa[3]);
    __asm__ volatile("s_waitcnt lgkmcnt(0)\n\ts_barrier" ::: "memory");

    if (writer) {
      float s = 0.f;
      #pragma unroll
      for (int q = 0; q < 16; ++q) s += pbuf[q][l];
      float hnew;
      if (tkn != PAD_IDX) {
        float pre = xv + s;
        float e = __builtin_amdgcn_exp2f(pre * 2.8853900817779268f);  // exp(2x)
        hnew = 1.0f - 2.0f / (e + 1.0f);                              // tanh(x)
      } else {
        hnew = prevh;  // register: race-free old h of own row
      }
      prevh = hnew;
      unsigned long long pv =
          ((unsigned long long)(unsigned int)(t + 1) << 32) |
          (unsigned long long)__builtin_bit_cast(unsigned int, hnew);
      __hip_atomic_store((((t + 1) & 1) ? hc1 : hc0) + j, pv,
                         __ATOMIC_RELAXED, __HIP_MEMORY_SCOPE_AGENT);
      h_all[((size_t)c * 256 + t) * 1024 + j] = f32_to_bf16_rne(hnew);
    }
  }
}

// ---------- kernel 4: logits GEMM — 8-phase schedule (m201 template port) ----------
// BM=BN=256 BK=64, 512 thr (8 waves 2Mx4N; per-wave 128x64). LDS 128KB = 2 buf.
// Per K-tile: 4 phases x {ds_reads(10/2/10/2), half-tile stage, bar, lgkm0,
// setprio, 16 MFMA, bar}. Staging cadence: P1/P2 stage B(kt+1) -> OTHER buf
// (its old reads retired at kt-1:P4); P4 stages A(kt+2) -> own buf (A reads
// retired by P3 lgkm0+bar). Counted vmcnt(4) ONLY at P4 (4 newest = A(kt+2)
// in flight; forces B(kt+1) landed). Tail: clamp stage to kt=15 (dead/identical
// bytes, uniform vmcnt math). L3 XCD remap + XOR swizzle + setprio kept.
__global__ __launch_bounds__(512) void gemm_kernel(const unsigned short* __restrict__ A,
                                                   const unsigned short* __restrict__ B,
                                                   float* __restrict__ C) {
  __shared__ unsigned short lds[2 * 32768];  // buf st: A @ st*32768, B @ +16384 (shorts)
  int tid = threadIdx.x;
  int lane = tid & 63, wave = tid >> 6;
  int bid = blockIdx.x;
  int x = bid & 7;               // XCD under round-robin dispatch
  int r = bid >> 3;              // 0..249 within XCD
  int tm = 2 * x + (r & 1);      // XCD owns 2 A-panels (L2-resident)
  int tn = r >> 1;               // B panel reused by 2 consecutive WGs
  int r0 = tm * 256, c0 = tn * 256;
  int wm = wave >> 2, wn = wave & 3;  // 2M x 4N; per-wave 128x64

  // stage one half-tile (2 loads/thread): mat 0=A,1=B; half = rows 128*half..+127
  auto SH = [&](int kt, int st, int mat, int half) {
    unsigned short* buf = (unsigned short*)lds + st * 32768 + mat * 16384 + half * 8192;
    const unsigned short* src = mat ? (B + (size_t)(c0 + half * 128) * 1024)
                                    : (A + (size_t)(r0 + half * 128) * 1024);
    #pragma unroll
    for (int i = 0; i < 2; ++i) {
      int slot = i * 512 + tid;        // 0..1023 = 128 rows x 8 granules
      int row = slot >> 3, sg = slot & 7;
      int kg = sg ^ (row & 7);         // half*128 ≡ 0 mod 8 -> same swizzle as reads
      const unsigned short* g = src + (size_t)row * 1024 + kt * 64 + kg * 8;
      load16_to_lds(g, &buf[(i * 512 + wave * 64) * 8]);
    }
  };

  f32x4 zero = {0.f, 0.f, 0.f, 0.f};
  f32x4 acc[8][4];
  #pragma unroll
  for (int i = 0; i < 8; ++i)
    #pragma unroll
    for (int jx = 0; jx < 4; ++jx) acc[i][jx] = zero;

  // prologue: tile0 (A+B) + tile1 A; drain; barrier
  SH(0, 0, 0, 0); SH(0, 0, 0, 1); SH(0, 0, 1, 0); SH(0, 0, 1, 1);
  SH(1, 1, 0, 0); SH(1, 1, 0, 1);
  __asm__ volatile("s_waitcnt vmcnt(0)" ::: "memory");
  __builtin_amdgcn_s_barrier();

  for (int kt = 0; kt < 16; ++kt) {
    int st = kt & 1;
    const char* bufA = (const char*)((const unsigned short*)lds + st * 32768);
    const char* bufB = bufA + 32768;  // bytes
    int ktB = kt + 1 > 15 ? 15 : kt + 1;   // clamped: dead/identical bytes on tail
    int ktA = kt + 2 > 15 ? 15 : kt + 2;
    int kb0 = (lane >> 4) * 16;            // kkb=0 kbyte
    int kb1 = 64 + kb0;                    // kkb=1 kbyte
    short8 af0[8], af1[8], bf0[4], bf1[4];

    // ---- P1: read af0[0..7], bf0[0..1]; stage B-low(kt+1) ----
    #pragma unroll
    for (int i = 0; i < 8; ++i) {
      int rowa = wm * 128 + i * 16 + (lane & 15);
      af0[i] = *(const short8*)(bufA + rowa * 128 + (kb0 ^ ((rowa & 7) << 4)));
    }
    #pragma unroll
    for (int jx = 0; jx < 2; ++jx) {
      int rowb = wn * 64 + jx * 16 + (lane & 15);
      bf0[jx] = *(const short8*)(bufB + rowb * 128 + (kb0 ^ ((rowb & 7) << 4)));
    }
    SH(ktB, st ^ 1, 1, 0);
    __builtin_amdgcn_s_barrier();
    __asm__ volatile("s_waitcnt lgkmcnt(0)" ::: "memory");
    __builtin_amdgcn_s_setprio(1);
    #pragma unroll
    for (int i = 0; i < 8; ++i)
      #pragma unroll
      for (int jx = 0; jx < 2; ++jx)
        acc[i][jx] = __builtin_amdgcn_mfma_f32_16x16x32_bf16(af0[i], bf0[jx], acc[i][jx], 0, 0, 0);
    __builtin_amdgcn_s_setprio(0);
    __builtin_amdgcn_s_barrier();

    // ---- P2: read bf0[2..3]; stage B-high(kt+1) ----
    #pragma unroll
    for (int jx = 2; jx < 4; ++jx) {
      int rowb = wn * 64 + jx * 16 + (lane & 15);
      bf0[jx] = *(const short8*)(bufB + rowb * 128 + (kb0 ^ ((rowb & 7) << 4)));
    }
    SH(ktB, st ^ 1, 1, 1);
    __builtin_amdgcn_s_barrier();
    __asm__ volatile("s_waitcnt lgkmcnt(0)" ::: "memory");
    __builtin_amdgcn_s_setprio(1);
    #pragma unroll
    for (int i = 0; i < 8; ++i)
      #pragma unroll
      for (int jx = 2; jx < 4; ++jx)
        acc[i][jx] = __builtin_amdgcn_mfma_f32_16x16x32_bf16(af0[i], bf0[jx], acc[i][jx], 0, 0, 0);
    __builtin_amdgcn_s_setprio(0);
    __builtin_amdgcn_s_barrier();

    // ---- P3: read af1[0..7], bf1[0..1] (A of tile kt now fully read) ----
    #pragma unroll
    for (int i = 0; i < 8; ++i) {
      int rowa = wm * 128 + i * 16 + (lane & 15);
      af1[i] = *(const short8*)(bufA + rowa * 128 + (kb1 ^ ((rowa & 7) << 4)));
    }
    #pragma unroll
    for (int jx = 0; jx < 2; ++jx) {
      int rowb = wn * 64 + jx * 16 + (lane & 15);
      bf1[jx] = *(const short8*)(bufB + rowb * 128 + (kb1 ^ ((rowb & 7) << 4)));
    }
    __builtin_amdgcn_s_barrier();
    __asm__ volatile("s_waitcnt lgkmcnt(0)" ::: "memory");
    __builtin_amdgcn_s_setprio(1);
    #pragma unroll
    for (int i = 0; i < 8; ++i)
      #pragma unroll
      for (int jx = 0; jx < 2; ++jx)
        acc[i][jx] = __builtin_amdgcn_mfma_f32_16x16x32_bf16(af1[i], bf1[jx], acc[i][jx], 0, 0, 0);
    __builtin_amdgcn_s_setprio(0);
    __builtin_amdgcn_s_barrier();

    // ---- P4: read bf1[2..3]; stage A(kt+2) both halves into own buf; vmcnt(4) ----
    #pragma unroll
    for (int jx = 2; jx < 4; ++jx) {
      int rowb = wn * 64 + jx * 16 + (lane & 15);
      bf1[jx] = *(const short8*)(bufB + rowb * 128 + (kb1 ^ ((rowb & 7) << 4)));
    }
    SH(ktA, st, 0, 0);
    SH(ktA, st, 0, 1);
    __builtin_amdgcn_s_barrier();
    __asm__ volatile("s_waitcnt lgkmcnt(0)" ::: "memory");
    __builtin_amdgcn_s_setprio(1);
    #pragma unroll
    for (int i = 0; i < 8; ++i)
      #pragma unroll
      for (int jx = 2; jx < 4; ++jx)
        acc[i][jx] = __builtin_amdgcn_mfma_f32_16x16x32_bf16(af1[i], bf1[jx], acc[i][jx], 0, 0, 0);
    __builtin_amdgcn_s_setprio(0);
    // counted: only A(kt+2)'s 4 loads may stay in flight -> B(kt+1) landed
    __asm__ volatile("s_waitcnt vmcnt(4)" ::: "memory");
    __builtin_amdgcn_s_barrier();
  }
  // drain ALL outstanding LDS-DMA before this WG can retire (LDS reassignment!)
  __asm__ volatile("s_waitcnt vmcnt(0)" ::: "memory");

  int rbase = r0 + wm * 128 + (lane >> 4) * 4;
  int cbase = c0 + wn * 64 + (lane & 15);
  #pragma unroll
  for (int i = 0; i < 8; ++i)
    #pragma unroll
    for (int jx = 0; jx < 4; ++jx)
      #pragma unroll
      for (int q = 0; q < 4; ++q)
        C[(size_t)(rbase + i * 16 + q) * 32000 + cbase + jx * 16] = acc[i][jx][q];
}

// ---------- launch ----------
extern "C" void kernel_launch(void* const* d_in, const int* in_sizes, int n_in,
                              void* d_out, int out_size, void* d_ws, size_t ws_size,
                              hipStream_t stream) {
  const int* tok = (const int*)d_in[0];
  const float* emb = (const float*)d_in[1];
  const float* Wx = (const float*)d_in[2];
  const float* Wh = (const float*)d_in[3];
  const float* bias = (const float*)d_in[4];
  const float* lmW = (const float*)d_in[5];
  float* out = (float*)d_out;

  const size_t OFF_LMW = 0;                       // bf16 lm_W: 65,536,000
  const size_t OFF_XW = 65536000;                 // f32 xw:   16,777,216
  const size_t OFF_HALL = OFF_XW + 16777216;      // bf16 h_all: 8,388,608
  const size_t OFF_HCMB = OFF_HALL + 8388608;     // u64 hcomb: 262,144
  const size_t NEED = OFF_HCMB + 262144;
  if (ws_size < NEED) {
    sentinel_kernel<<<1, 1, 0, stream>>>(out);
    return;
  }
  char* ws = (char*)d_ws;
  unsigned short* lmW_bf = (unsigned short*)(ws + OFF_LMW);
  float* xw = (float*)(ws + OFF_XW);
  unsigned short* h_all = (unsigned short*)(ws + OFF_HALL);
  unsigned long long* hcomb = (unsigned long long*)(ws + OFF_HCMB);

  // tags must restart at 0 EVERY call (graph replay!)
  hipMemsetAsync(ws + OFF_HCMB, 0, 262144, stream);
  xwcvt_kernel<<<1536, 256, 0, stream>>>(tok, emb, Wx, bias, xw, lmW, lmW_bf);
  rec_kernel<<<256, 1024, 0, stream>>>(Wh, xw, tok, hcomb, h_all);
  gemm_kernel<<<2000, 512, 0, stream>>>(h_all, lmW_bf, out);
}

// Round 17
// 862.683 us; speedup vs baseline: 3.7644x; 1.0067x over previous
//
#include <hip/hip_runtime.h>

#define PAD_IDX 0

typedef __attribute__((ext_vector_type(8))) short short8;
typedef __attribute__((ext_vector_type(4))) float f32x4;

// ---------- helpers ----------
__device__ __forceinline__ unsigned short f32_to_bf16_rne(float f) {
  unsigned int u = __builtin_bit_cast(unsigned int, f);
  u += 0x7FFFu + ((u >> 16) & 1u);
  return (unsigned short)(u >> 16);
}

__device__ __forceinline__ void load16_to_lds(const void* g, void* lds) {
  __builtin_amdgcn_global_load_lds(
      (const __attribute__((address_space(1))) unsigned int*)g,
      (__attribute__((address_space(3))) unsigned int*)lds,
      16, 0, 0);
}

// ---------- kernel 0: sentinel (only if ws too small) ----------
__global__ void sentinel_kernel(float* out) { out[0] = 1.0e6f; }

// ---------- kernel 1: merged xw(f32) + cvt + hcomb-zero ----------
// R16 lesson: xw MUST stay f32 — bf16 rounding of the pre-activation
// propagates ~linearly through the 256-step tanh chain (absmax 0.031 > thr).
// Blocks 0..1023: f32 xw 64x64 tiles (proven). Blocks 1024..1535: lm_W cvt
// grid-stride; blocks 1024..1039 also zero hcomb (replaces memset dispatch;
// stream order => done before rec launches; every call => graph-replay safe).
__global__ __launch_bounds__(256) void xwcvt_kernel(const int* __restrict__ tok,
                                                    const float* __restrict__ emb,
                                                    const float* __restrict__ Wx,
                                                    const float* __restrict__ bias,
                                                    float* __restrict__ xw,
                                                    const float* __restrict__ lmW,
                                                    unsigned short* __restrict__ lmW_bf,
                                                    unsigned long long* hcomb) {
  int tid = threadIdx.x;
  if (blockIdx.x >= 1024) {
    if (blockIdx.x < 1040) {  // hcomb zero: 16 blk x 256 thr x 8 u64 = 262144 B
      size_t base = ((size_t)(blockIdx.x - 1024) * 256 + tid) * 8;
      #pragma unroll
      for (int q = 0; q < 8; ++q) hcomb[base + q] = 0ull;
    }
    const int n8 = 32000 * 1024 / 8;
    int stride = 512 * 256;
    for (int i = (blockIdx.x - 1024) * 256 + tid; i < n8; i += stride) {
      float4 a = ((const float4*)lmW)[2 * i];
      float4 b = ((const float4*)lmW)[2 * i + 1];
      ushort4 lo, hi;
      lo.x = f32_to_bf16_rne(a.x); lo.y = f32_to_bf16_rne(a.y);
      lo.z = f32_to_bf16_rne(a.z); lo.w = f32_to_bf16_rne(a.w);
      hi.x = f32_to_bf16_rne(b.x); hi.y = f32_to_bf16_rne(b.y);
      hi.z = f32_to_bf16_rne(b.z); hi.w = f32_to_bf16_rne(b.w);
      ((ushort4*)lmW_bf)[2 * i] = lo;
      ((ushort4*)lmW_bf)[2 * i + 1] = hi;
    }
    return;
  }
  __shared__ float At[32][68];
  __shared__ float Bt[32][68];
  __shared__ int stok[64];
  int tm = blockIdx.x & 63;
  int tn = blockIdx.x >> 6;
  int r0 = tm * 64, j0 = tn * 64;
  if (tid < 64) stok[tid] = tok[r0 + tid];
  int tx = tid & 15, ty = tid >> 4;
  float acc[4][4] = {};
  for (int kt = 0; kt < 512; kt += 32) {
    __syncthreads();
    #pragma unroll
    for (int ii = 0; ii < 2; ++ii) {
      int idx = tid * 2 + ii;
      int m = idx >> 3, fv = idx & 7;
      float4 va = *(const float4*)&emb[(size_t)stok[m] * 512 + kt + fv * 4];
      float4 vb = *(const float4*)&Wx[(size_t)(j0 + m) * 512 + kt + fv * 4];
      At[fv * 4 + 0][m] = va.x; At[fv * 4 + 1][m] = va.y;
      At[fv * 4 + 2][m] = va.z; At[fv * 4 + 3][m] = va.w;
      Bt[fv * 4 + 0][m] = vb.x; Bt[fv * 4 + 1][m] = vb.y;
      Bt[fv * 4 + 2][m] = vb.z; Bt[fv * 4 + 3][m] = vb.w;
    }
    __syncthreads();
    #pragma unroll
    for (int k = 0; k < 32; ++k) {
      float4 a4 = *(const float4*)&At[k][ty * 4];
      float4 b4 = *(const float4*)&Bt[k][tx * 4];
      float av[4] = {a4.x, a4.y, a4.z, a4.w};
      float bv[4] = {b4.x, b4.y, b4.z, b4.w};
      #pragma unroll
      for (int i = 0; i < 4; ++i)
        #pragma unroll
        for (int jj = 0; jj < 4; ++jj) acc[i][jj] = fmaf(av[i], bv[jj], acc[i][jj]);
    }
  }
  #pragma unroll
  for (int i = 0; i < 4; ++i) {
    size_t row = (size_t)(r0 + ty * 4 + i) * 1024 + j0 + tx * 4;
    #pragma unroll
    for (int jj = 0; jj < 4; ++jj)
      xw[row + jj] = acc[i][jj] + bias[j0 + tx * 4 + jj];
  }
}

// ---------- kernel 3: recurrence (exact R10 structure — proven 453-457 us x4) ----------
__global__ __launch_bounds__(1024, 4) void rec_kernel(const float* __restrict__ Wh,
                                                      const float* __restrict__ xw,
                                                      const int* __restrict__ tok,
                                                      unsigned long long* hcomb,  // [2][16][1024]
                                                      unsigned short* __restrict__ h_all) {
  int c = blockIdx.x & 15;
  int g = blockIdx.x >> 4;
  int tid = threadIdx.x;
  int w = tid >> 6;
  int l = tid & 63;
  int j = g * 64 + l;

  const float* wb = Wh + (size_t)j * 1024 + w * 64;
#define LDW(i) f32x4 w##i = *(const f32x4*)(wb + i * 4);
  LDW(0) LDW(1) LDW(2) LDW(3) LDW(4) LDW(5) LDW(6) LDW(7)
  LDW(8) LDW(9) LDW(10) LDW(11) LDW(12) LDW(13) LDW(14) LDW(15)
#undef LDW

  __shared__ float hs[16][64];
  __shared__ float pbuf[16][64];
  unsigned long long* hc0 = hcomb + (size_t)c * 1024;
  unsigned long long* hc1 = hcomb + 16 * 1024 + (size_t)c * 1024;
  bool writer = (w == 0);
  float prevh = 0.f;

  for (int t = 0; t < 256; ++t) {
    float xv = 0.f;
    int tkn = 1;
    if (writer) {
      xv = xw[((size_t)c * 256 + t) * 1024 + j];
      tkn = tok[c * 256 + t];
    }
    unsigned long long* src = ((t & 1) ? hc1 : hc0) + tid;
    unsigned long long v;
    int guard = 0;
    do {
      v = __hip_atomic_load(src, __ATOMIC_RELAXED, __HIP_MEMORY_SCOPE_AGENT);
      if ((unsigned int)(v >> 32) == (unsigned int)t) break;
      __builtin_amdgcn_s_sleep(1);
    } while (++guard < (1 << 20));  // fail loud, not hung
    hs[w][l] = __builtin_bit_cast(float, (unsigned int)v);
    __asm__ volatile("s_waitcnt lgkmcnt(0)" ::: "memory");  // wave-local share

    const float* hp = &hs[w][0];
    f32x4 a0 = {0.f, 0.f, 0.f, 0.f}, a1 = a0, a2 = a0, a3 = a0;
#define FMAI(i, acc) { f32x4 h4 = *(const f32x4*)(hp + i * 4); acc += w##i * h4; }
    FMAI(0, a0) FMAI(1, a1) FMAI(2, a2) FMAI(3, a3)
    FMAI(4, a0) FMAI(5, a1) FMAI(6, a2) FMAI(7, a3)
    FMAI(8, a0) FMAI(9, a1) FMAI(10, a2) FMAI(11, a3)
    FMAI(12, a0) FMAI(13, a1) FMAI(14, a2) FMAI(15, a3)
#undef FMAI
    f32x4 aa = (a0 + a1) + (a2 + a3);
    pbuf[w][l] = (aa[0] + aa[1]) + (aa[2] + aa[3]);
    __asm__ volatile("s_waitcnt lgkmcnt(0)\n\ts_barrier" ::: "memory");

    if (writer) {
      float s = 0.f;
      #pragma unroll
      for (int q = 0; q < 16; ++q) s += pbuf[q][l];
      float hnew;
      if (tkn != PAD_IDX) {
        float pre = xv + s;
        float e = __builtin_amdgcn_exp2f(pre * 2.8853900817779268f);  // exp(2x)
        hnew = 1.0f - 2.0f / (e + 1.0f);                              // tanh(x)
      } else {
        hnew = prevh;  // register: race-free old h of own row
      }
      prevh = hnew;
      unsigned long long pv =
          ((unsigned long long)(unsigned int)(t + 1) << 32) |
          (unsigned long long)__builtin_bit_cast(unsigned int, hnew);
      __hip_atomic_store((((t + 1) & 1) ? hc1 : hc0) + j, pv,
                         __ATOMIC_RELAXED, __HIP_MEMORY_SCOPE_AGENT);
      h_all[((size_t)c * 256 + t) * 1024 + j] = f32_to_bf16_rne(hnew);
    }
  }
}

// ---------- kernel 4: logits GEMM — 8-phase schedule (R15, kept) ----------
__global__ __launch_bounds__(512) void gemm_kernel(const unsigned short* __restrict__ A,
                                                   const unsigned short* __restrict__ B,
                                                   float* __restrict__ C) {
  __shared__ unsigned short lds[2 * 32768];
  int tid = threadIdx.x;
  int lane = tid & 63, wave = tid >> 6;
  int bid = blockIdx.x;
  int x = bid & 7;
  int r = bid >> 3;
  int tm = 2 * x + (r & 1);
  int tn = r >> 1;
  int r0 = tm * 256, c0 = tn * 256;
  int wm = wave >> 2, wn = wave & 3;

  auto SH = [&](int kt, int st, int mat, int half) {
    unsigned short* buf = (unsigned short*)lds + st * 32768 + mat * 16384 + half * 8192;
    const unsigned short* src = mat ? (B + (size_t)(c0 + half * 128) * 1024)
                                    : (A + (size_t)(r0 + half * 128) * 1024);
    #pragma unroll
    for (int i = 0; i < 2; ++i) {
      int slot = i * 512 + tid;
      int row = slot >> 3, sg = slot & 7;
      int kg = sg ^ (row & 7);
      const unsigned short* g = src + (size_t)row * 1024 + kt * 64 + kg * 8;
      load16_to_lds(g, &buf[(i * 512 + wave * 64) * 8]);
    }
  };

  f32x4 zero = {0.f, 0.f, 0.f, 0.f};
  f32x4 acc[8][4];
  #pragma unroll
  for (int i = 0; i < 8; ++i)
    #pragma unroll
    for (int jx = 0; jx < 4; ++jx) acc[i][jx] = zero;

  SH(0, 0, 0, 0); SH(0, 0, 0, 1); SH(0, 0, 1, 0); SH(0, 0, 1, 1);
  SH(1, 1, 0, 0); SH(1, 1, 0, 1);
  __asm__ volatile("s_waitcnt vmcnt(0)" ::: "memory");
  __builtin_amdgcn_s_barrier();

  for (int kt = 0; kt < 16; ++kt) {
    int st = kt & 1;
    const char* bufA = (const char*)((const unsigned short*)lds + st * 32768);
    const char* bufB = bufA + 32768;
    int ktB = kt + 1 > 15 ? 15 : kt + 1;
    int ktA = kt + 2 > 15 ? 15 : kt + 2;
    int kb0 = (lane >> 4) * 16;
    int kb1 = 64 + kb0;
    short8 af0[8], af1[8], bf0[4], bf1[4];

    #pragma unroll
    for (int i = 0; i < 8; ++i) {
      int rowa = wm * 128 + i * 16 + (lane & 15);
      af0[i] = *(const short8*)(bufA + rowa * 128 + (kb0 ^ ((rowa & 7) << 4)));
    }
    #pragma unroll
    for (int jx = 0; jx < 2; ++jx) {
      int rowb = wn * 64 + jx * 16 + (lane & 15);
      bf0[jx] = *(const short8*)(bufB + rowb * 128 + (kb0 ^ ((rowb & 7) << 4)));
    }
    SH(ktB, st ^ 1, 1, 0);
    __builtin_amdgcn_s_barrier();
    __asm__ volatile("s_waitcnt lgkmcnt(0)" ::: "memory");
    __builtin_amdgcn_s_setprio(1);
    #pragma unroll
    for (int i = 0; i < 8; ++i)
      #pragma unroll
      for (int jx = 0; jx < 2; ++jx)
        acc[i][jx] = __builtin_amdgcn_mfma_f32_16x16x32_bf16(af0[i], bf0[jx], acc[i][jx], 0, 0, 0);
    __builtin_amdgcn_s_setprio(0);
    __builtin_amdgcn_s_barrier();

    #pragma unroll
    for (int jx = 2; jx < 4; ++jx) {
      int rowb = wn * 64 + jx * 16 + (lane & 15);
      bf0[jx] = *(const short8*)(bufB + rowb * 128 + (kb0 ^ ((rowb & 7) << 4)));
    }
    SH(ktB, st ^ 1, 1, 1);
    __builtin_amdgcn_s_barrier();
    __asm__ volatile("s_waitcnt lgkmcnt(0)" ::: "memory");
    __builtin_amdgcn_s_setprio(1);
    #pragma unroll
    for (int i = 0; i < 8; ++i)
      #pragma unroll
      for (int jx = 2; jx < 4; ++jx)
        acc[i][jx] = __builtin_amdgcn_mfma_f32_16x16x32_bf16(af0[i], bf0[jx], acc[i][jx], 0, 0, 0);
    __builtin_amdgcn_s_setprio(0);
    __builtin_amdgcn_s_barrier();

    #pragma unroll
    for (int i = 0; i < 8; ++i) {
      int rowa = wm * 128 + i * 16 + (lane & 15);
      af1[i] = *(const short8*)(bufA + rowa * 128 + (kb1 ^ ((rowa & 7) << 4)));
    }
    #pragma unroll
    for (int jx = 0; jx < 2; ++jx) {
      int rowb = wn * 64 + jx * 16 + (lane & 15);
      bf1[jx] = *(const short8*)(bufB + rowb * 128 + (kb1 ^ ((rowb & 7) << 4)));
    }
    __builtin_amdgcn_s_barrier();
    __asm__ volatile("s_waitcnt lgkmcnt(0)" ::: "memory");
    __builtin_amdgcn_s_setprio(1);
    #pragma unroll
    for (int i = 0; i < 8; ++i)
      #pragma unroll
      for (int jx = 0; jx < 2; ++jx)
        acc[i][jx] = __builtin_amdgcn_mfma_f32_16x16x32_bf16(af1[i], bf1[jx], acc[i][jx], 0, 0, 0);
    __builtin_amdgcn_s_setprio(0);
    __builtin_amdgcn_s_barrier();

    #pragma unroll
    for (int jx = 2; jx < 4; ++jx) {
      int rowb = wn * 64 + jx * 16 + (lane & 15);
      bf1[jx] = *(const short8*)(bufB + rowb * 128 + (kb1 ^ ((rowb & 7) << 4)));
    }
    SH(ktA, st, 0, 0);
    SH(ktA, st, 0, 1);
    __builtin_amdgcn_s_barrier();
    __asm__ volatile("s_waitcnt lgkmcnt(0)" ::: "memory");
    __builtin_amdgcn_s_setprio(1);
    #pragma unroll
    for (int i = 0; i < 8; ++i)
      #pragma unroll
      for (int jx = 2; jx < 4; ++jx)
        acc[i][jx] = __builtin_amdgcn_mfma_f32_16x16x32_bf16(af1[i], bf1[jx], acc[i][jx], 0, 0, 0);
    __builtin_amdgcn_s_setprio(0);
    __asm__ volatile("s_waitcnt vmcnt(4)" ::: "memory");
    __builtin_amdgcn_s_barrier();
  }
  __asm__ volatile("s_waitcnt vmcnt(0)" ::: "memory");

  int rbase = r0 + wm * 128 + (lane >> 4) * 4;
  int cbase = c0 + wn * 64 + (lane & 15);
  #pragma unroll
  for (int i = 0; i < 8; ++i)
    #pragma unroll
    for (int jx = 0; jx < 4; ++jx)
      #pragma unroll
      for (int q = 0; q < 4; ++q)
        C[(size_t)(rbase + i * 16 + q) * 32000 + cbase + jx * 16] = acc[i][jx][q];
}

// ---------- launch ----------
extern "C" void kernel_launch(void* const* d_in, const int* in_sizes, int n_in,
                              void* d_out, int out_size, void* d_ws, size_t ws_size,
                              hipStream_t stream) {
  const int* tok = (const int*)d_in[0];
  const float* emb = (const float*)d_in[1];
  const float* Wx = (const float*)d_in[2];
  const float* Wh = (const float*)d_in[3];
  const float* bias = (const float*)d_in[4];
  const float* lmW = (const float*)d_in[5];
  float* out = (float*)d_out;

  const size_t OFF_LMW = 0;                       // bf16 lm_W: 65,536,000
  const size_t OFF_XW = 65536000;                 // f32 xw:   16,777,216
  const size_t OFF_HALL = OFF_XW + 16777216;      // bf16 h_all: 8,388,608
  const size_t OFF_HCMB = OFF_HALL + 8388608;     // u64 hcomb: 262,144
  const size_t NEED = OFF_HCMB + 262144;
  if (ws_size < NEED) {
    sentinel_kernel<<<1, 1, 0, stream>>>(out);
    return;
  }
  char* ws = (char*)d_ws;
  unsigned short* lmW_bf = (unsigned short*)(ws + OFF_LMW);
  float* xw = (float*)(ws + OFF_XW);
  unsigned short* h_all = (unsigned short*)(ws + OFF_HALL);
  unsigned long long* hcomb = (unsigned long long*)(ws + OFF_HCMB);

  // hcomb zeroing folded into xwcvt (blocks 1024..1039) — every call (graph replay)
  xwcvt_kernel<<<1536, 256, 0, stream>>>(tok, emb, Wx, bias, xw, lmW, lmW_bf, hcomb);
  rec_kernel<<<256, 1024, 0, stream>>>(Wh, xw, tok, hcomb, h_all);
  gemm_kernel<<<2000, 512, 0, stream>>>(h_all, lmW_bf, out);
}